// Round 4
// baseline (51.495 us; speedup 1.0000x reference)
//
#include <hip/hip_runtime.h>

// Problem constants
#define N_  32
#define C_  32
#define H_  56
#define W_  56
#define O_  32
#define HP_ 58   // padded
#define WP_ 58
#define HW_ (H_*W_)          // 3136
#define CHW_ (C_*H_*W_)      // 100352
#define KK_ 9
#define CKK_ (C_*KK_)        // 288

// xT layout: [C][HP][WP][N] (zero padded border), bf16
#define XT_ELEMS ((size_t)C_*HP_*WP_*N_)

typedef __bf16 bf16x8 __attribute__((ext_vector_type(8)));
typedef float  f32x4  __attribute__((ext_vector_type(4)));

// -------- transpose + pad + bf16-convert:  x[N][C][H][W] -> xT[C][HP][WP][N] --------
__global__ __launch_bounds__(256) void xpose_kernel(const float* __restrict__ x,
                                                    __bf16* __restrict__ xT) {
    const int c = blockIdx.x;   // 0..31
    const int y = blockIdx.y;   // 0..57 (padded row)
    __shared__ float sbuf[32 * 57];   // [n][col], row stride 57
    const int tid = threadIdx.x;
    const bool interior = (y >= 1) && (y <= H_);
    if (interior) {
        for (int idx = tid; idx < N_ * W_; idx += 256) {
            int n = idx / W_;
            int col = idx - n * W_;
            sbuf[n * 57 + col] = x[((size_t)(n * C_ + c) * H_ + (y - 1)) * W_ + col];
        }
    }
    __syncthreads();
    __bf16* dst = xT + ((size_t)(c * HP_ + y)) * WP_ * N_;
    for (int idx = tid; idx < WP_ * N_; idx += 256) {
        int xx = idx >> 5;        // 0..57
        int n  = idx & 31;
        float v = 0.f;
        if (interior && xx >= 1 && xx <= W_) v = sbuf[n * 57 + (xx - 1)];
        dst[idx] = (__bf16)v;
    }
}

// -------- MFMA main --------
// Per position (h,w): C[n=32][o=32] = sum_k A[n][k] * Wt[o][k], k = c*9+i*3+j (K=288)
// Wave = (w, n-half): 8 x-gathers/step (own 16 n's), BOTH o-halves' weights
// (4 float4; duplicate instrs across n-half waves hit L1), 2 MFMA/step.
// Block = 4 waves = 2 adjacent w x 2 n-halves. Grid = 28 w-tiles * 56 h = 1568.
__global__ __launch_bounds__(256, 6) void lc2d_mfma(const float* __restrict__ wgt,
                                                    const __bf16* __restrict__ xT,
                                                    const float* __restrict__ bias,
                                                    float* __restrict__ out) {
    __shared__ int offs[288];
    __shared__ __align__(16) float sbuf[32][33][2];   // [n][o pad33][w2]

    const int tid = threadIdx.x;
    // x-gather offset table (position-independent), in elements
    for (int k = tid; k < 288; k += 256) {
        int c = k / 9, ij = k - 9 * c;
        int i = ij / 3, j = ij - 3 * i;
        offs[k] = c * (HP_ * WP_ * N_) + i * (WP_ * N_) + j * N_;
    }
    __syncthreads();

    // bijective XCD-chunk swizzle: 1568 blocks = 8 XCDs x 196 consecutive wg ids
    const int flat = blockIdx.x;
    const int wg = (flat & 7) * 196 + (flat >> 3);
    const int wt = wg % 28;          // w-tile of 2 (w-major => adjacent tiles same XCD)
    const int h  = wg / 28;          // 0..55
    const int wave = tid >> 6;       // 0..3
    const int lane = tid & 63;
    const int dw = wave & 1;         // which w of the pair
    const int nh = wave >> 1;        // which n-half this wave computes
    const int w  = wt * 2 + dw;
    const int q = lane >> 4;         // k-group 0..3
    const int r = lane & 15;         // o (B-frag) / n (A-frag) within tile

    // B (weight) bases: lane reads 8 consecutive fp32 of row o=r and o=r+16
    const float* wb0 = wgt + ((size_t)(r * HW_ + h * W_ + w)) * CKK_ + 8 * q;
    const float* wb1 = wb0 + (size_t)16 * HW_ * CKK_;
    // A base: n = nh*16 + r
    const __bf16* ab = xT + (h * WP_ + w) * N_ + nh * 16 + r;

    f32x4 acc0 = {0.f, 0.f, 0.f, 0.f};   // o 0..15
    f32x4 acc1 = {0.f, 0.f, 0.f, 0.f};   // o 16..31

    #pragma unroll 3
    for (int s = 0; s < 9; ++s) {
        const int4 ov0 = *(const int4*)&offs[32 * s + 8 * q];
        const int4 ov1 = *(const int4*)&offs[32 * s + 8 * q + 4];
        const float4 b0a = *(const float4*)(wb0 + 32 * s);
        const float4 b0b = *(const float4*)(wb0 + 32 * s + 4);
        const float4 b1a = *(const float4*)(wb1 + 32 * s);
        const float4 b1b = *(const float4*)(wb1 + 32 * s + 4);

        const int offv[8] = {ov0.x, ov0.y, ov0.z, ov0.w, ov1.x, ov1.y, ov1.z, ov1.w};
        bf16x8 af, bf0, bf1;
        #pragma unroll
        for (int t = 0; t < 8; ++t) af[t] = ab[offv[t]];

        bf0[0] = (__bf16)b0a.x; bf0[1] = (__bf16)b0a.y; bf0[2] = (__bf16)b0a.z; bf0[3] = (__bf16)b0a.w;
        bf0[4] = (__bf16)b0b.x; bf0[5] = (__bf16)b0b.y; bf0[6] = (__bf16)b0b.z; bf0[7] = (__bf16)b0b.w;
        bf1[0] = (__bf16)b1a.x; bf1[1] = (__bf16)b1a.y; bf1[2] = (__bf16)b1a.z; bf1[3] = (__bf16)b1a.w;
        bf1[4] = (__bf16)b1b.x; bf1[5] = (__bf16)b1b.y; bf1[6] = (__bf16)b1b.z; bf1[7] = (__bf16)b1b.w;

        acc0 = __builtin_amdgcn_mfma_f32_16x16x32_bf16(af, bf0, acc0, 0, 0, 0);
        acc1 = __builtin_amdgcn_mfma_f32_16x16x32_bf16(af, bf1, acc1, 0, 0, 0);
    }

    // stage C into LDS: C[m][col]: m = q*4+reg -> n = nh*16 + m; col = r -> o (half ot)
    #pragma unroll
    for (int ot = 0; ot < 2; ++ot) {
        f32x4 a = ot == 0 ? acc0 : acc1;
        const int o = ot * 16 + r;
        #pragma unroll
        for (int reg = 0; reg < 4; ++reg) {
            const int n = nh * 16 + q * 4 + reg;
            sbuf[n][o][dw] = a[reg];
        }
    }
    __syncthreads();

    // store: float2 over {w0, w0+1} per (n,o), + bias
    const int w0 = wt * 2;
    #pragma unroll
    for (int rr = 0; rr < 4; ++rr) {
        const int fl = rr * 256 + tid;   // 0..1023 -> (n,o)
        const int n = fl >> 5;
        const int o = fl & 31;
        float2 v = *(const float2*)&sbuf[n][o][0];
        const float2 bv = *(const float2*)(bias + o * HW_ + h * W_ + w0);
        v.x += bv.x; v.y += bv.y;
        *(float2*)(out + (size_t)n * CHW_ + o * HW_ + h * W_ + w0) = v;
    }
}

// -------- fallback (if workspace too small): thread per output, bounds-checked --------
__global__ __launch_bounds__(256) void lc2d_naive(const float* __restrict__ x,
                                                  const float* __restrict__ wgt,
                                                  const float* __restrict__ bias,
                                                  float* __restrict__ out) {
    int idx = blockIdx.x * 256 + threadIdx.x;
    const int total = N_ * O_ * H_ * W_;
    if (idx >= total) return;
    int w = idx % W_;
    int h = (idx / W_) % H_;
    int o = (idx / HW_) % O_;
    int n = idx / CHW_;
    const float* wp = wgt + ((size_t)((o * H_ + h) * W_ + w)) * CKK_;
    float s = 0.f;
    for (int c = 0; c < C_; ++c) {
        for (int i = 0; i < 3; ++i) {
            int yy = h + i - 1;
            if (yy < 0 || yy >= H_) continue;
            for (int j = 0; j < 3; ++j) {
                int xx = w + j - 1;
                if (xx < 0 || xx >= W_) continue;
                s = fmaf(wp[c * KK_ + i * 3 + j],
                         x[((size_t)(n * C_ + c) * H_ + yy) * W_ + xx], s);
            }
        }
    }
    out[idx] = s + bias[idx % CHW_];
}

extern "C" void kernel_launch(void* const* d_in, const int* in_sizes, int n_in,
                              void* d_out, int out_size, void* d_ws, size_t ws_size,
                              hipStream_t stream) {
    const float* x    = (const float*)d_in[0];
    const float* wgt  = (const float*)d_in[1];
    const float* bias = (const float*)d_in[2];
    float* out = (float*)d_out;

    const size_t need = XT_ELEMS * sizeof(__bf16);
    if (ws_size >= need) {
        __bf16* xT = (__bf16*)d_ws;
        hipLaunchKernelGGL(xpose_kernel, dim3(C_, HP_), dim3(256), 0, stream, x, xT);
        hipLaunchKernelGGL(lc2d_mfma, dim3(1568), dim3(256), 0, stream, wgt, xT, bias, out);
    } else {
        int total = N_ * O_ * H_ * W_;
        hipLaunchKernelGGL(lc2d_naive, dim3((total + 255) / 256), dim3(256), 0, stream,
                           x, wgt, bias, out);
    }
}

// Round 5
// 42.087 us; speedup vs baseline: 1.2235x; 1.2235x over previous
//
#include <hip/hip_runtime.h>

// Problem constants
#define N_  32
#define C_  32
#define H_  56
#define W_  56
#define O_  32
#define HP_ 58   // padded
#define WP_ 58
#define HW_ (H_*W_)          // 3136
#define CHW_ (C_*H_*W_)      // 100352
#define KK_ 9
#define CKK_ (C_*KK_)        // 288

// xT layout: [C][HP][WP][N] (zero padded border), bf16
#define XT_ELEMS ((size_t)C_*HP_*WP_*N_)

typedef __bf16 bf16x8 __attribute__((ext_vector_type(8)));
typedef float  f32x4  __attribute__((ext_vector_type(4)));

// -------- transpose + pad + bf16-convert:  x[N][C][H][W] -> xT[C][HP][WP][N] --------
__global__ __launch_bounds__(256) void xpose_kernel(const float* __restrict__ x,
                                                    __bf16* __restrict__ xT) {
    const int c = blockIdx.x;   // 0..31
    const int y = blockIdx.y;   // 0..57 (padded row)
    __shared__ float sbuf[32 * 57];   // [n][col], row stride 57
    const int tid = threadIdx.x;
    const bool interior = (y >= 1) && (y <= H_);
    if (interior) {
        for (int idx = tid; idx < N_ * W_; idx += 256) {
            int n = idx / W_;
            int col = idx - n * W_;
            sbuf[n * 57 + col] = x[((size_t)(n * C_ + c) * H_ + (y - 1)) * W_ + col];
        }
    }
    __syncthreads();
    __bf16* dst = xT + ((size_t)(c * HP_ + y)) * WP_ * N_;
    for (int idx = tid; idx < WP_ * N_; idx += 256) {
        int xx = idx >> 5;        // 0..57
        int n  = idx & 31;
        float v = 0.f;
        if (interior && xx >= 1 && xx <= W_) v = sbuf[n * 57 + (xx - 1)];
        dst[idx] = (__bf16)v;
    }
}

// -------- MFMA main --------
// Per position (h,w): C[n=32][o=32] = sum_k A[n][k] * Wt[o][k], k = c*9+i*3+j (K=288)
// Wave = (w, o-half): 16 x-gathers/step (both n-halves via offset:32 fold),
// own o-half weights (2 float4/step), 2 MFMA/step.
// Block = 4 waves = 2 adjacent w x 2 o-halves. Grid = 28 w-tiles * 56 h = 1568.
// K-loop FULLY UNROLLED: deep MLP is the whole game (round-4 post-mortem:
// VGPR=28 from launch_bounds(256,6) serialized gathers into 4-load batches).
__global__ __launch_bounds__(256) void lc2d_mfma(const float* __restrict__ wgt,
                                                 const __bf16* __restrict__ xT,
                                                 const float* __restrict__ bias,
                                                 float* __restrict__ out) {
    __shared__ int offs[288];
    __shared__ __align__(16) float sbuf[32][33][2];   // [n][o pad33][w2]

    const int tid = threadIdx.x;
    // x-gather offset table (position-independent), in elements
    for (int k = tid; k < 288; k += 256) {
        int c = k / 9, ij = k - 9 * c;
        int i = ij / 3, j = ij - 3 * i;
        offs[k] = c * (HP_ * WP_ * N_) + i * (WP_ * N_) + j * N_;
    }
    __syncthreads();

    // bijective XCD-chunk swizzle: 1568 blocks = 8 XCDs x 196 consecutive wg ids
    const int flat = blockIdx.x;
    const int wg = (flat & 7) * 196 + (flat >> 3);
    const int wt = wg % 28;          // w-tile of 2 (w-major => adjacent tiles same XCD)
    const int h  = wg / 28;          // 0..55
    const int wave = tid >> 6;       // 0..3
    const int lane = tid & 63;
    const int dw = wave & 1;         // which w of the pair
    const int oh = wave >> 1;        // which o-half
    const int w  = wt * 2 + dw;
    const int q = lane >> 4;         // k-group 0..3
    const int r = lane & 15;         // o (B-frag) / n (A-frag) within tile

    // B (weight) base: lane reads 8 consecutive fp32 of row o = oh*16 + r
    const float* wb = wgt + ((size_t)((oh * 16 + r) * HW_ + h * W_ + w)) * CKK_ + 8 * q;
    // A base: n = r (and +16 elements => n = r+16)
    const __bf16* ab = xT + (h * WP_ + w) * N_ + r;

    f32x4 acc0 = {0.f, 0.f, 0.f, 0.f};   // n 0..15
    f32x4 acc1 = {0.f, 0.f, 0.f, 0.f};   // n 16..31

    #pragma unroll
    for (int s = 0; s < 9; ++s) {
        const int4 ov0 = *(const int4*)&offs[32 * s + 8 * q];
        const int4 ov1 = *(const int4*)&offs[32 * s + 8 * q + 4];
        const float4 ba = *(const float4*)(wb + 32 * s);
        const float4 bb = *(const float4*)(wb + 32 * s + 4);

        const int offv[8] = {ov0.x, ov0.y, ov0.z, ov0.w, ov1.x, ov1.y, ov1.z, ov1.w};
        bf16x8 af0, af1, bfB;
        #pragma unroll
        for (int t = 0; t < 8; ++t) {
            const __bf16* p = ab + offv[t];
            af0[t] = p[0];     // n = r
            af1[t] = p[16];    // n = r+16 (offset:32 fold, same addr reg)
        }
        bfB[0] = (__bf16)ba.x; bfB[1] = (__bf16)ba.y; bfB[2] = (__bf16)ba.z; bfB[3] = (__bf16)ba.w;
        bfB[4] = (__bf16)bb.x; bfB[5] = (__bf16)bb.y; bfB[6] = (__bf16)bb.z; bfB[7] = (__bf16)bb.w;

        acc0 = __builtin_amdgcn_mfma_f32_16x16x32_bf16(af0, bfB, acc0, 0, 0, 0);
        acc1 = __builtin_amdgcn_mfma_f32_16x16x32_bf16(af1, bfB, acc1, 0, 0, 0);
    }

    // stage C into LDS: n = mt*16 + q*4 + reg, o = oh*16 + r (layout verified round 2)
    #pragma unroll
    for (int mt = 0; mt < 2; ++mt) {
        f32x4 a = mt == 0 ? acc0 : acc1;
        const int o = oh * 16 + r;
        #pragma unroll
        for (int reg = 0; reg < 4; ++reg) {
            const int n = mt * 16 + q * 4 + reg;
            sbuf[n][o][dw] = a[reg];
        }
    }
    __syncthreads();

    // store: float2 over {w0, w0+1} per (n,o), + bias
    const int w0 = wt * 2;
    #pragma unroll
    for (int rr = 0; rr < 4; ++rr) {
        const int fl = rr * 256 + tid;   // 0..1023 -> (n,o)
        const int n = fl >> 5;
        const int o = fl & 31;
        float2 v = *(const float2*)&sbuf[n][o][0];
        const float2 bv = *(const float2*)(bias + o * HW_ + h * W_ + w0);
        v.x += bv.x; v.y += bv.y;
        *(float2*)(out + (size_t)n * CHW_ + o * HW_ + h * W_ + w0) = v;
    }
}

// -------- fallback (if workspace too small): thread per output, bounds-checked --------
__global__ __launch_bounds__(256) void lc2d_naive(const float* __restrict__ x,
                                                  const float* __restrict__ wgt,
                                                  const float* __restrict__ bias,
                                                  float* __restrict__ out) {
    int idx = blockIdx.x * 256 + threadIdx.x;
    const int total = N_ * O_ * H_ * W_;
    if (idx >= total) return;
    int w = idx % W_;
    int h = (idx / W_) % H_;
    int o = (idx / HW_) % O_;
    int n = idx / CHW_;
    const float* wp = wgt + ((size_t)((o * H_ + h) * W_ + w)) * CKK_;
    float s = 0.f;
    for (int c = 0; c < C_; ++c) {
        for (int i = 0; i < 3; ++i) {
            int yy = h + i - 1;
            if (yy < 0 || yy >= H_) continue;
            for (int j = 0; j < 3; ++j) {
                int xx = w + j - 1;
                if (xx < 0 || xx >= W_) continue;
                s = fmaf(wp[c * KK_ + i * 3 + j],
                         x[((size_t)(n * C_ + c) * H_ + yy) * W_ + xx], s);
            }
        }
    }
    out[idx] = s + bias[idx % CHW_];
}

extern "C" void kernel_launch(void* const* d_in, const int* in_sizes, int n_in,
                              void* d_out, int out_size, void* d_ws, size_t ws_size,
                              hipStream_t stream) {
    const float* x    = (const float*)d_in[0];
    const float* wgt  = (const float*)d_in[1];
    const float* bias = (const float*)d_in[2];
    float* out = (float*)d_out;

    const size_t need = XT_ELEMS * sizeof(__bf16);
    if (ws_size >= need) {
        __bf16* xT = (__bf16*)d_ws;
        hipLaunchKernelGGL(xpose_kernel, dim3(C_, HP_), dim3(256), 0, stream, x, xT);
        hipLaunchKernelGGL(lc2d_mfma, dim3(1568), dim3(256), 0, stream, wgt, xT, bias, out);
    } else {
        int total = N_ * O_ * H_ * W_;
        hipLaunchKernelGGL(lc2d_naive, dim3((total + 255) / 256), dim3(256), 0, stream,
                           x, wgt, bias, out);
    }
}

// Round 6
// 41.705 us; speedup vs baseline: 1.2347x; 1.0092x over previous
//
#include <hip/hip_runtime.h>

// Problem constants
#define N_  32
#define C_  32
#define H_  56
#define W_  56
#define O_  32
#define HP_ 58   // padded
#define WP_ 58
#define HW_ (H_*W_)          // 3136
#define CHW_ (C_*H_*W_)      // 100352
#define KK_ 9
#define CKK_ (C_*KK_)        // 288

// xT layout: [C][HP][WP][N] (zero padded border), bf16
#define XT_ELEMS ((size_t)C_*HP_*WP_*N_)

#define KP_   144   // k-pairs (288/2)
#define PSTR_ 36    // uints per kp-row: 32 n + 4 pad (16B-aligned rows, 2-way banks)

typedef __bf16 bf16x8 __attribute__((ext_vector_type(8)));
typedef float  f32x4  __attribute__((ext_vector_type(4)));

// -------- transpose + pad + bf16-convert:  x[N][C][H][W] -> xT[C][HP][WP][N] --------
__global__ __launch_bounds__(256) void xpose_kernel(const float* __restrict__ x,
                                                    __bf16* __restrict__ xT) {
    const int c = blockIdx.x;   // 0..31
    const int y = blockIdx.y;   // 0..57 (padded row)
    __shared__ float sbuf[32 * 57];   // [n][col], row stride 57
    const int tid = threadIdx.x;
    const bool interior = (y >= 1) && (y <= H_);
    if (interior) {
        for (int idx = tid; idx < N_ * W_; idx += 256) {
            int n = idx / W_;
            int col = idx - n * W_;
            sbuf[n * 57 + col] = x[((size_t)(n * C_ + c) * H_ + (y - 1)) * W_ + col];
        }
    }
    __syncthreads();
    __bf16* dst = xT + ((size_t)(c * HP_ + y)) * WP_ * N_;
    for (int idx = tid; idx < WP_ * N_; idx += 256) {
        int xx = idx >> 5;        // 0..57
        int n  = idx & 31;
        float v = 0.f;
        if (interior && xx >= 1 && xx <= W_) v = sbuf[n * 57 + (xx - 1)];
        dst[idx] = (__bf16)v;
    }
}

// -------- MFMA main --------
// Per position (h,w): C[n=32][o=32] = sum_k A[n][k] * Wt[o][k], k = c*9+ij (K=288)
// Block = 2 adjacent w x (2 o-half waves each). Block first builds an LDS im2col
// tile P2[dw][kp][n]: uint = bf16 pair (k=2kp, 2kp+1) at batch n. Build is fully
// coalesced both sides (16B global reads, uint4 LDS writes, in-reg interleave).
// Main loop A-frag = 8 x ds_read_b32 at immediate offsets (2-way banks = free);
// weight = 2 x float4/step, read exactly once globally. 2 MFMA/step, 9 steps.
__global__ __launch_bounds__(256) void lc2d_mfma(const float* __restrict__ wgt,
                                                 const __bf16* __restrict__ xT,
                                                 const float* __restrict__ bias,
                                                 float* __restrict__ out) {
    __shared__ int offs[288];
    __shared__ unsigned P2[2 * KP_ * PSTR_];          // 41472 B
    __shared__ __align__(16) float sbuf[32][33][2];   // 8448 B

    const int tid = threadIdx.x;
    // x-gather offset table (position-independent), in elements
    for (int k = tid; k < 288; k += 256) {
        int c = k / 9, ij = k - 9 * c;
        int i = ij / 3, j = ij - 3 * i;
        offs[k] = c * (HP_ * WP_ * N_) + i * (WP_ * N_) + j * N_;
    }
    __syncthreads();

    // bijective XCD-chunk swizzle: 1568 blocks = 8 XCDs x 196 consecutive wg ids
    const int flat = blockIdx.x;
    const int wg = (flat & 7) * 196 + (flat >> 3);
    const int wt = wg % 28;          // w-tile of 2
    const int h  = wg / 28;          // 0..55
    const int w0 = wt * 2;

    // ---- build P2 (coalesced): task = dw*576 + kp*4 + g (g = n-oct) ----
    const __bf16* xbase = xT + (h * WP_ + w0) * N_;
    for (int task = tid; task < 1152; task += 256) {
        const int dw  = task / 576;
        const int rem = task - dw * 576;
        const int kp  = rem >> 2;
        const int g   = rem & 3;
        const __bf16* s0 = xbase + dw * N_ + offs[2 * kp]     + 8 * g;
        const __bf16* s1 = xbase + dw * N_ + offs[2 * kp + 1] + 8 * g;
        union { uint4 q; ushort s[8]; } ua, ub;
        ua.q = *(const uint4*)s0;
        ub.q = *(const uint4*)s1;
        unsigned o0[8];
        #pragma unroll
        for (int m = 0; m < 8; ++m)
            o0[m] = (unsigned)ua.s[m] | ((unsigned)ub.s[m] << 16);
        unsigned* dst = &P2[(dw * KP_ + kp) * PSTR_ + 8 * g];
        *(uint4*)(dst)     = make_uint4(o0[0], o0[1], o0[2], o0[3]);
        *(uint4*)(dst + 4) = make_uint4(o0[4], o0[5], o0[6], o0[7]);
    }
    __syncthreads();

    const int wave = tid >> 6;       // 0..3
    const int lane = tid & 63;
    const int dw = wave & 1;         // which w of the pair
    const int oh = wave >> 1;        // which o-half
    const int w  = w0 + dw;
    const int q = lane >> 4;         // k-group 0..3
    const int r = lane & 15;         // o (B-frag) / n (A-frag) within tile

    // B (weight) base: lane reads 8 consecutive fp32 of row o = oh*16 + r
    const float* wb = wgt + ((size_t)((oh * 16 + r) * HW_ + h * W_ + w)) * CKK_ + 8 * q;
    // A base in LDS: kp = 4q (+16s per step, +d per pair), n = r
    const unsigned* pa = &P2[(dw * KP_ + 4 * q) * PSTR_ + r];

    f32x4 acc0 = {0.f, 0.f, 0.f, 0.f};   // n 0..15
    f32x4 acc1 = {0.f, 0.f, 0.f, 0.f};   // n 16..31

    #pragma unroll
    for (int s = 0; s < 9; ++s) {
        union { unsigned u[4]; bf16x8 v; } a0, a1;
        #pragma unroll
        for (int d = 0; d < 4; ++d) {
            a0.u[d] = pa[s * (16 * PSTR_) + d * PSTR_];        // n = r
            a1.u[d] = pa[s * (16 * PSTR_) + d * PSTR_ + 16];   // n = r+16
        }
        const float4 ba = *(const float4*)(wb + 32 * s);
        const float4 bb = *(const float4*)(wb + 32 * s + 4);
        bf16x8 bfB;
        bfB[0] = (__bf16)ba.x; bfB[1] = (__bf16)ba.y; bfB[2] = (__bf16)ba.z; bfB[3] = (__bf16)ba.w;
        bfB[4] = (__bf16)bb.x; bfB[5] = (__bf16)bb.y; bfB[6] = (__bf16)bb.z; bfB[7] = (__bf16)bb.w;

        acc0 = __builtin_amdgcn_mfma_f32_16x16x32_bf16(a0.v, bfB, acc0, 0, 0, 0);
        acc1 = __builtin_amdgcn_mfma_f32_16x16x32_bf16(a1.v, bfB, acc1, 0, 0, 0);
    }

    // stage C into LDS: n = mt*16 + q*4 + reg, o = oh*16 + r (layout verified round 2)
    #pragma unroll
    for (int mt = 0; mt < 2; ++mt) {
        f32x4 a = mt == 0 ? acc0 : acc1;
        const int o = oh * 16 + r;
        #pragma unroll
        for (int reg = 0; reg < 4; ++reg) {
            const int n = mt * 16 + q * 4 + reg;
            sbuf[n][o][dw] = a[reg];
        }
    }
    __syncthreads();

    // store: float2 over {w0, w0+1} per (n,o), + bias
    #pragma unroll
    for (int rr = 0; rr < 4; ++rr) {
        const int fl = rr * 256 + tid;   // 0..1023 -> (n,o)
        const int n = fl >> 5;
        const int o = fl & 31;
        float2 v = *(const float2*)&sbuf[n][o][0];
        const float2 bv = *(const float2*)(bias + o * HW_ + h * W_ + w0);
        v.x += bv.x; v.y += bv.y;
        *(float2*)(out + (size_t)n * CHW_ + o * HW_ + h * W_ + w0) = v;
    }
}

// -------- fallback (if workspace too small): thread per output, bounds-checked --------
__global__ __launch_bounds__(256) void lc2d_naive(const float* __restrict__ x,
                                                  const float* __restrict__ wgt,
                                                  const float* __restrict__ bias,
                                                  float* __restrict__ out) {
    int idx = blockIdx.x * 256 + threadIdx.x;
    const int total = N_ * O_ * H_ * W_;
    if (idx >= total) return;
    int w = idx % W_;
    int h = (idx / W_) % H_;
    int o = (idx / HW_) % O_;
    int n = idx / CHW_;
    const float* wp = wgt + ((size_t)((o * H_ + h) * W_ + w)) * CKK_;
    float s = 0.f;
    for (int c = 0; c < C_; ++c) {
        for (int i = 0; i < 3; ++i) {
            int yy = h + i - 1;
            if (yy < 0 || yy >= H_) continue;
            for (int j = 0; j < 3; ++j) {
                int xx = w + j - 1;
                if (xx < 0 || xx >= W_) continue;
                s = fmaf(wp[c * KK_ + i * 3 + j],
                         x[((size_t)(n * C_ + c) * H_ + yy) * W_ + xx], s);
            }
        }
    }
    out[idx] = s + bias[idx % CHW_];
}

extern "C" void kernel_launch(void* const* d_in, const int* in_sizes, int n_in,
                              void* d_out, int out_size, void* d_ws, size_t ws_size,
                              hipStream_t stream) {
    const float* x    = (const float*)d_in[0];
    const float* wgt  = (const float*)d_in[1];
    const float* bias = (const float*)d_in[2];
    float* out = (float*)d_out;

    const size_t need = XT_ELEMS * sizeof(__bf16);
    if (ws_size >= need) {
        __bf16* xT = (__bf16*)d_ws;
        hipLaunchKernelGGL(xpose_kernel, dim3(C_, HP_), dim3(256), 0, stream, x, xT);
        hipLaunchKernelGGL(lc2d_mfma, dim3(1568), dim3(256), 0, stream, wgt, xT, bias, out);
    } else {
        int total = N_ * O_ * H_ * W_;
        hipLaunchKernelGGL(lc2d_naive, dim3((total + 255) / 256), dim3(256), 0, stream,
                           x, wgt, bias, out);
    }
}